// Round 1
// baseline (2169.018 us; speedup 1.0000x reference)
//
#include <hip/hip_runtime.h>
#include <hip/hip_bf16.h>
#include <cmath>

#define BB 1024
#define SS 512
#define DD 768
#define F3 2304   // 3*D
#define H1 256
#define H2 64

// ---------------------------------------------------------------------------
// Kernel 1: span means (parts 0,1) + cls copy (part 2) -> feat[B][2304]
// grid = (3, B), block = 192 threads (each thread owns one float4 column)
// ---------------------------------------------------------------------------
__global__ __launch_bounds__(192) void span_feat_kernel(
    const float* __restrict__ x,
    const int* __restrict__ e1,
    const int* __restrict__ e2,
    float* __restrict__ feat)
{
    const int part = blockIdx.x;       // 0: e1, 1: e2, 2: cls
    const int b    = blockIdx.y;
    const int t    = threadIdx.x;      // 0..191
    const size_t xbase = (size_t)b * (SS * DD);
    float* frow = feat + (size_t)b * F3;

    if (part == 2) {
        const float4 v = *(const float4*)(x + xbase + t * 4);
        *(float4*)(frow + 2 * DD + t * 4) = v;
        return;
    }

    const int* sp = (part == 0) ? e1 : e2;
    const int lo = sp[2 * b];
    int hi = sp[2 * b + 1];
    if (hi < lo + 1) hi = lo + 1;
    const int n = hi - lo;

    const float* p0 = x + xbase + (size_t)lo * DD + t * 4;
    float4 acc = make_float4(0.f, 0.f, 0.f, 0.f);
    int i = 0;
    for (; i + 4 <= n; i += 4) {
        const float* q = p0 + (size_t)i * DD;
        const float4 a = *(const float4*)(q);
        const float4 c = *(const float4*)(q + DD);
        const float4 d = *(const float4*)(q + 2 * DD);
        const float4 e = *(const float4*)(q + 3 * DD);
        acc.x += (a.x + c.x) + (d.x + e.x);
        acc.y += (a.y + c.y) + (d.y + e.y);
        acc.z += (a.z + c.z) + (d.z + e.z);
        acc.w += (a.w + c.w) + (d.w + e.w);
    }
    for (; i < n; ++i) {
        const float4 a = *(const float4*)(p0 + (size_t)i * DD);
        acc.x += a.x; acc.y += a.y; acc.z += a.z; acc.w += a.w;
    }
    const float inv = 1.0f / (float)n;
    float4 r;
    r.x = acc.x * inv; r.y = acc.y * inv; r.z = acc.z * inv; r.w = acc.w * inv;
    *(float4*)(frow + part * DD + t * 4) = r;
}

// ---------------------------------------------------------------------------
// Kernel 2: h1 = relu(feat @ W1 + b1)   (1024x2304 @ 2304x256)
// grid = 128 blocks, block = 256 threads; M-tile = 8 rows, each thread = 1 col
// ---------------------------------------------------------------------------
#define MT 8
#define KC 32
__global__ __launch_bounds__(256) void mlp1_kernel(
    const float* __restrict__ feat,
    const float* __restrict__ W1,
    const float* __restrict__ b1,
    float* __restrict__ h1)
{
    __shared__ float lds[MT][KC];
    const int m0 = blockIdx.x * MT;
    const int n  = threadIdx.x;          // output column 0..255

    float acc[MT];
#pragma unroll
    for (int m = 0; m < MT; ++m) acc[m] = 0.f;

    const int mm = threadIdx.x / KC;     // one element per thread per chunk
    const int kk_ld = threadIdx.x % KC;

    for (int k0 = 0; k0 < F3; k0 += KC) {
        __syncthreads();
        lds[mm][kk_ld] = feat[(size_t)(m0 + mm) * F3 + k0 + kk_ld];
        __syncthreads();
#pragma unroll
        for (int kk = 0; kk < KC; ++kk) {
            const float w = W1[(size_t)(k0 + kk) * H1 + n];
#pragma unroll
            for (int m = 0; m < MT; ++m) acc[m] += lds[m][kk] * w;
        }
    }

    const float bias = b1[n];
#pragma unroll
    for (int m = 0; m < MT; ++m) {
        float v = acc[m] + bias;
        h1[(size_t)(m0 + m) * H1 + n] = v > 0.f ? v : 0.f;
    }
}

// ---------------------------------------------------------------------------
// Kernel 3: per-batch head: h2 = relu(h1 @ W2 + b2); logits = h2 @ W3 + b3;
//           out = softmax(logits). One wave (64 lanes) per batch, 4 batches/block.
// grid = 256 blocks, block = 256 threads
// ---------------------------------------------------------------------------
__global__ __launch_bounds__(256) void head_kernel(
    const float* __restrict__ h1,
    const float* __restrict__ W2,
    const float* __restrict__ b2,
    const float* __restrict__ W3,
    const float* __restrict__ b3,
    float* __restrict__ out)
{
    __shared__ float hs[4][H1];
    const int wave = threadIdx.x >> 6;        // 0..3  (local batch)
    const int lane = threadIdx.x & 63;        // 0..63
    const int b = blockIdx.x * 4 + wave;

    // stage h1 row into LDS (each lane loads a float4 -> 64*4 = 256 floats)
    *(float4*)&hs[wave][lane * 4] = *(const float4*)&h1[(size_t)b * H1 + lane * 4];
    __syncthreads();

    // h2[lane] = relu(b2[lane] + sum_k hs[k] * W2[k][lane])
    float acc = b2[lane];
#pragma unroll 8
    for (int k = 0; k < H1; ++k) {
        acc += hs[wave][k] * W2[(size_t)k * H2 + lane];
    }
    const float h2v = acc > 0.f ? acc : 0.f;

    // partial logits: lane contributes h2[lane] * W3[lane][0..3]
    const float4 w3 = *(const float4*)&W3[lane * 4];
    float p0 = h2v * w3.x, p1 = h2v * w3.y, p2 = h2v * w3.z, p3 = h2v * w3.w;
#pragma unroll
    for (int off = 32; off > 0; off >>= 1) {
        p0 += __shfl_xor(p0, off);
        p1 += __shfl_xor(p1, off);
        p2 += __shfl_xor(p2, off);
        p3 += __shfl_xor(p3, off);
    }

    if (lane == 0) {
        const float l0 = p0 + b3[0];
        const float l1 = p1 + b3[1];
        const float l2 = p2 + b3[2];
        const float l3 = p3 + b3[3];
        const float mx = fmaxf(fmaxf(l0, l1), fmaxf(l2, l3));
        const float e0 = expf(l0 - mx);
        const float e1 = expf(l1 - mx);
        const float e2 = expf(l2 - mx);
        const float e3 = expf(l3 - mx);
        const float inv = 1.0f / (e0 + e1 + e2 + e3);
        *(float4*)&out[(size_t)b * 4] = make_float4(e0 * inv, e1 * inv, e2 * inv, e3 * inv);
    }
}

extern "C" void kernel_launch(void* const* d_in, const int* in_sizes, int n_in,
                              void* d_out, int out_size, void* d_ws, size_t ws_size,
                              hipStream_t stream) {
    const float* x  = (const float*)d_in[0];
    const int*   e1 = (const int*)  d_in[1];
    const int*   e2 = (const int*)  d_in[2];
    const float* W1 = (const float*)d_in[3];
    const float* b1 = (const float*)d_in[4];
    const float* W2 = (const float*)d_in[5];
    const float* b2 = (const float*)d_in[6];
    const float* W3 = (const float*)d_in[7];
    const float* b3 = (const float*)d_in[8];
    float* out = (float*)d_out;

    float* feat = (float*)d_ws;                       // B * 2304 floats
    float* h1   = feat + (size_t)BB * F3;             // B * 256 floats

    span_feat_kernel<<<dim3(3, BB), 192, 0, stream>>>(x, e1, e2, feat);
    mlp1_kernel<<<BB / MT, 256, 0, stream>>>(feat, W1, b1, h1);
    head_kernel<<<BB / 4, 256, 0, stream>>>(h1, W2, b2, W3, b3, out);
}